// Round 2
// baseline (68.133 us; speedup 1.0000x reference)
//
#include <hip/hip_runtime.h>

// BarrelShifter8: out[row][j] = (j >= k) ? P[row][j-k] : 0, k = 4*s2 + 2*s1 + s0.
// mux(s,a,b) on binary inputs == (s ? a : b); the three mux+shift stages compose
// into a single barrel shift by k bits.
//
// R1 lesson: thread-per-row grid-stride at VGPR=12 had only one row's loads in
// flight -> latency-bound (HBM 13-33% of peak, VALUBusy 7%). Fix: manual 4x
// unroll with interleaved rows (tid + m*stride) so 8x dwordx4 + 12x dword loads
// are outstanding per iteration while coalescing stays perfect.

__global__ __launch_bounds__(256) void barrel_shifter8_kernel(
    const float* __restrict__ P,   // (N, 8), values exactly 0.0f or 1.0f
    const float* __restrict__ S,   // (N, 3), values exactly 0.0f or 1.0f
    float*       __restrict__ out, // (N, 8)
    int N)
{
    const int tid    = blockIdx.x * blockDim.x + threadIdx.x;
    const int stride = gridDim.x * blockDim.x;

    // Process one row: pack 8 binary floats -> bits, shift, unpack.
    auto shift_row = [](float4 a, float4 b, float s0, float s1, float s2,
                        float4& o0, float4& o1) {
        int k = (s2 >= 0.5f ? 4 : 0) + (s1 >= 0.5f ? 2 : 0) + (s0 >= 0.5f ? 1 : 0);
        unsigned bits =
            (a.x >= 0.5f ?   1u : 0u) | (a.y >= 0.5f ?   2u : 0u) |
            (a.z >= 0.5f ?   4u : 0u) | (a.w >= 0.5f ?   8u : 0u) |
            (b.x >= 0.5f ?  16u : 0u) | (b.y >= 0.5f ?  32u : 0u) |
            (b.z >= 0.5f ?  64u : 0u) | (b.w >= 0.5f ? 128u : 0u);
        unsigned sh = (bits << k) & 0xFFu;
        o0.x = (sh &   1u) ? 1.0f : 0.0f;
        o0.y = (sh &   2u) ? 1.0f : 0.0f;
        o0.z = (sh &   4u) ? 1.0f : 0.0f;
        o0.w = (sh &   8u) ? 1.0f : 0.0f;
        o1.x = (sh &  16u) ? 1.0f : 0.0f;
        o1.y = (sh &  32u) ? 1.0f : 0.0f;
        o1.z = (sh &  64u) ? 1.0f : 0.0f;
        o1.w = (sh & 128u) ? 1.0f : 0.0f;
    };

    int base = tid;
    // Full 4-row unrolled iterations: all 20 loads issued before compute/stores.
    for (; (long long)base + 3LL * stride < N; base += 4 * stride) {
        const int r0 = base, r1 = base + stride, r2 = base + 2 * stride, r3 = base + 3 * stride;

        const float4* p0 = reinterpret_cast<const float4*>(P + (size_t)r0 * 8);
        const float4* p1 = reinterpret_cast<const float4*>(P + (size_t)r1 * 8);
        const float4* p2 = reinterpret_cast<const float4*>(P + (size_t)r2 * 8);
        const float4* p3 = reinterpret_cast<const float4*>(P + (size_t)r3 * 8);
        float4 a0 = p0[0], b0 = p0[1];
        float4 a1 = p1[0], b1 = p1[1];
        float4 a2 = p2[0], b2 = p2[1];
        float4 a3 = p3[0], b3 = p3[1];

        const float* sp0 = S + (size_t)r0 * 3;
        const float* sp1 = S + (size_t)r1 * 3;
        const float* sp2 = S + (size_t)r2 * 3;
        const float* sp3 = S + (size_t)r3 * 3;
        float s00 = sp0[0], s01 = sp0[1], s02 = sp0[2];
        float s10 = sp1[0], s11 = sp1[1], s12 = sp1[2];
        float s20 = sp2[0], s21 = sp2[1], s22 = sp2[2];
        float s30 = sp3[0], s31 = sp3[1], s32 = sp3[2];

        float4 o00, o01, o10, o11, o20, o21, o30, o31;
        shift_row(a0, b0, s00, s01, s02, o00, o01);
        shift_row(a1, b1, s10, s11, s12, o10, o11);
        shift_row(a2, b2, s20, s21, s22, o20, o21);
        shift_row(a3, b3, s30, s31, s32, o30, o31);

        float4* q0 = reinterpret_cast<float4*>(out + (size_t)r0 * 8);
        float4* q1 = reinterpret_cast<float4*>(out + (size_t)r1 * 8);
        float4* q2 = reinterpret_cast<float4*>(out + (size_t)r2 * 8);
        float4* q3 = reinterpret_cast<float4*>(out + (size_t)r3 * 8);
        q0[0] = o00; q0[1] = o01;
        q1[0] = o10; q1[1] = o11;
        q2[0] = o20; q2[1] = o21;
        q3[0] = o30; q3[1] = o31;
    }

    // Tail: single-row path.
    for (int row = base; row < N; row += stride) {
        const float4* p4 = reinterpret_cast<const float4*>(P + (size_t)row * 8);
        float4 a = p4[0], b = p4[1];
        const float* s = S + (size_t)row * 3;
        float4 o0, o1;
        shift_row(a, b, s[0], s[1], s[2], o0, o1);
        float4* q4 = reinterpret_cast<float4*>(out + (size_t)row * 8);
        q4[0] = o0; q4[1] = o1;
    }
}

extern "C" void kernel_launch(void* const* d_in, const int* in_sizes, int n_in,
                              void* d_out, int out_size, void* d_ws, size_t ws_size,
                              hipStream_t stream) {
    const float* P = (const float*)d_in[0];
    const float* S = (const float*)d_in[1];
    float* out = (float*)d_out;

    int N = in_sizes[0] / 8;  // rows

    const int block = 256;
    int needed = (N + block - 1) / block;
    int grid = needed < 2048 ? needed : 2048;  // memory-bound: cap + grid-stride

    barrel_shifter8_kernel<<<grid, block, 0, stream>>>(P, S, out, N);
}

// Round 4
// 63.447 us; speedup vs baseline: 1.0739x; 1.0739x over previous
//
#include <hip/hip_runtime.h>

// BarrelShifter8: out[row][j] = (j >= k) ? P[row][j-k] : 0, k = 4*s2 + 2*s1 + s0.
// mux(s,a,b) on binary {0,1} inputs == (s ? a : b); the three mux+shift stages
// compose into a single barrel shift by k bits.
//
// R1: thread-per-row grid-stride, VGPR=12 -> 62 us (best). R2: 4x unroll
// REGRESSED (68 us, occupancy down) -> reverted. R3: nontemporal builtin
// rejects HIP_vector_type* -> use native clang ext_vector float4. Theory: NT
// stores keep the 128 MiB output stream out of L2/L3 so P/S (176 MiB) stay
// L3-resident; writes stream to HBM.

typedef float vfloat4 __attribute__((ext_vector_type(4)));

__global__ __launch_bounds__(256) void barrel_shifter8_kernel(
    const vfloat4* __restrict__ P4,  // (N, 8) floats viewed as (N, 2) float4
    const float*   __restrict__ S,   // (N, 3), values exactly 0.0f or 1.0f
    vfloat4*       __restrict__ out4,// (N, 8) floats viewed as (N, 2) float4
    int N)
{
    int row = blockIdx.x * 256 + threadIdx.x;
    if (row >= N) return;

    // Coalesced 32 B row load as two float4.
    vfloat4 a = P4[(size_t)row * 2];
    vfloat4 b = P4[(size_t)row * 2 + 1];

    // S row: 3 scalar loads; wave's 64 lanes cover a contiguous, fully-used span.
    const float* s = S + (size_t)row * 3;
    float s0 = s[0];
    float s1 = s[1];
    float s2 = s[2];

    int k = (s2 >= 0.5f ? 4 : 0) + (s1 >= 0.5f ? 2 : 0) + (s0 >= 0.5f ? 1 : 0);

    // Pack the 8 binary floats into bits; barrel shift; unpack with
    // compile-time-constant bit tests (no runtime-indexed reg array).
    unsigned bits =
        (a.x >= 0.5f ?   1u : 0u) | (a.y >= 0.5f ?   2u : 0u) |
        (a.z >= 0.5f ?   4u : 0u) | (a.w >= 0.5f ?   8u : 0u) |
        (b.x >= 0.5f ?  16u : 0u) | (b.y >= 0.5f ?  32u : 0u) |
        (b.z >= 0.5f ?  64u : 0u) | (b.w >= 0.5f ? 128u : 0u);

    unsigned sh = (bits << k) & 0xFFu;

    vfloat4 o0, o1;
    o0.x = (sh &   1u) ? 1.0f : 0.0f;
    o0.y = (sh &   2u) ? 1.0f : 0.0f;
    o0.z = (sh &   4u) ? 1.0f : 0.0f;
    o0.w = (sh &   8u) ? 1.0f : 0.0f;
    o1.x = (sh &  16u) ? 1.0f : 0.0f;
    o1.y = (sh &  32u) ? 1.0f : 0.0f;
    o1.z = (sh &  64u) ? 1.0f : 0.0f;
    o1.w = (sh & 128u) ? 1.0f : 0.0f;

    // Non-temporal: output is never re-read; don't pollute L2/L3 with it.
    __builtin_nontemporal_store(o0, out4 + (size_t)row * 2);
    __builtin_nontemporal_store(o1, out4 + (size_t)row * 2 + 1);
}

extern "C" void kernel_launch(void* const* d_in, const int* in_sizes, int n_in,
                              void* d_out, int out_size, void* d_ws, size_t ws_size,
                              hipStream_t stream) {
    const vfloat4* P4 = (const vfloat4*)d_in[0];
    const float*   S  = (const float*)d_in[1];
    vfloat4* out4 = (vfloat4*)d_out;

    int N = in_sizes[0] / 8;  // rows

    const int block = 256;
    int grid = (N + block - 1) / block;  // one thread per row, no loop

    barrel_shifter8_kernel<<<grid, block, 0, stream>>>(P4, S, out4, N);
}

// Round 5
// 59.828 us; speedup vs baseline: 1.1388x; 1.0605x over previous
//
#include <hip/hip_runtime.h>

// BarrelShifter8: out[row][j] = (j >= k) ? P[row][j-k] : 0, k = 4*s2 + 2*s1 + s0.
// mux(s,a,b) on binary {0,1} inputs == (s ? a : b); the three mux+shift stages
// compose into a single barrel shift by k bits.
//
// History: R1 thread-per-row grid-stride = 62.3 us (best). R2 4x unroll
// regressed (occupancy). R4 non-temporal stores regressed (WRITE_SIZE
// 131->150 MB, FETCH unchanged -> MALL churn not avoidable from ISA).
// R5: one thread per row, exact grid, plain float4 loads/stores. Memory-bound:
// 304 MiB logical traffic; 62 us = 5.1 TB/s = ~81% of the 6.29 TB/s copy
// ceiling with a 3-stream mix -> near mixed-stream roofline.

typedef float vfloat4 __attribute__((ext_vector_type(4)));

__global__ __launch_bounds__(256) void barrel_shifter8_kernel(
    const vfloat4* __restrict__ P4,  // (N, 8) floats viewed as (N, 2) float4
    const float*   __restrict__ S,   // (N, 3), values exactly 0.0f or 1.0f
    vfloat4*       __restrict__ out4,// (N, 8) floats viewed as (N, 2) float4
    int N)
{
    int row = blockIdx.x * 256 + threadIdx.x;
    if (row >= N) return;

    // Coalesced 32 B row load as two float4.
    vfloat4 a = P4[(size_t)row * 2];
    vfloat4 b = P4[(size_t)row * 2 + 1];

    // S row: 3 scalar loads; wave's 64 lanes cover a contiguous, fully-used span.
    const float* s = S + (size_t)row * 3;
    float s0 = s[0];
    float s1 = s[1];
    float s2 = s[2];

    int k = (s2 >= 0.5f ? 4 : 0) + (s1 >= 0.5f ? 2 : 0) + (s0 >= 0.5f ? 1 : 0);

    // Pack the 8 binary floats into bits; barrel shift; unpack with
    // compile-time-constant bit tests (no runtime-indexed reg array).
    unsigned bits =
        (a.x >= 0.5f ?   1u : 0u) | (a.y >= 0.5f ?   2u : 0u) |
        (a.z >= 0.5f ?   4u : 0u) | (a.w >= 0.5f ?   8u : 0u) |
        (b.x >= 0.5f ?  16u : 0u) | (b.y >= 0.5f ?  32u : 0u) |
        (b.z >= 0.5f ?  64u : 0u) | (b.w >= 0.5f ? 128u : 0u);

    unsigned sh = (bits << k) & 0xFFu;

    vfloat4 o0, o1;
    o0.x = (sh &   1u) ? 1.0f : 0.0f;
    o0.y = (sh &   2u) ? 1.0f : 0.0f;
    o0.z = (sh &   4u) ? 1.0f : 0.0f;
    o0.w = (sh &   8u) ? 1.0f : 0.0f;
    o1.x = (sh &  16u) ? 1.0f : 0.0f;
    o1.y = (sh &  32u) ? 1.0f : 0.0f;
    o1.z = (sh &  64u) ? 1.0f : 0.0f;
    o1.w = (sh & 128u) ? 1.0f : 0.0f;

    out4[(size_t)row * 2]     = o0;
    out4[(size_t)row * 2 + 1] = o1;
}

extern "C" void kernel_launch(void* const* d_in, const int* in_sizes, int n_in,
                              void* d_out, int out_size, void* d_ws, size_t ws_size,
                              hipStream_t stream) {
    const vfloat4* P4 = (const vfloat4*)d_in[0];
    const float*   S  = (const float*)d_in[1];
    vfloat4* out4 = (vfloat4*)d_out;

    int N = in_sizes[0] / 8;  // rows

    const int block = 256;
    int grid = (N + block - 1) / block;  // one thread per row, no loop

    barrel_shifter8_kernel<<<grid, block, 0, stream>>>(P4, S, out4, N);
}